// Round 7
// baseline (242.951 us; speedup 1.0000x reference)
//
#include <hip/hip_runtime.h>
#include <hip/hip_bf16.h>
#include <cstdint>
#include <cstddef>

typedef __bf16 bf16_t;
typedef __bf16 bf16x8 __attribute__((ext_vector_type(8)));
typedef __bf16 bf16x4 __attribute__((ext_vector_type(4)));
typedef float f32x4 __attribute__((ext_vector_type(4)));

#define MFMA16(a, b, c) __builtin_amdgcn_mfma_f32_16x16x32_bf16((a), (b), (c), 0, 0, 0)

__device__ __forceinline__ bf16x8 ld8f(const float* p) {
    f32x4 a = *reinterpret_cast<const f32x4*>(p);
    f32x4 b = *reinterpret_cast<const f32x4*>(p + 4);
    bf16x8 r;
    r[0] = (bf16_t)a[0]; r[1] = (bf16_t)a[1]; r[2] = (bf16_t)a[2]; r[3] = (bf16_t)a[3];
    r[4] = (bf16_t)b[0]; r[5] = (bf16_t)b[1]; r[6] = (bf16_t)b[2]; r[7] = (bf16_t)b[3];
    return r;
}
__device__ __forceinline__ bf16x8 ldg8(const bf16_t* p) {
    return *reinterpret_cast<const bf16x8*>(p);
}
// async global->LDS DMA, 16B/lane; lds dest = uniform base + lane*16B
__device__ __forceinline__ void gload_lds16(const bf16_t* g, bf16_t* l) {
    __builtin_amdgcn_global_load_lds((const __attribute__((address_space(1))) void*)g,
                                     (__attribute__((address_space(3))) void*)l, 16, 0, 0);
}

// ---------------------------------------------------------------------------
// K0 k_prep: blocks 0..255 = fused-weight GEMM (W bf16[1024][1024]);
//            blocks 256..8447 = pack/convert H,Z f32 -> A bf16[16384][1024].
// ---------------------------------------------------------------------------
__global__ __launch_bounds__(256) void k_prep(
    const float* __restrict__ H, const float* __restrict__ Z,
    const float* __restrict__ Whk, const float* __restrict__ Whv,
    const float* __restrict__ Wzk, const float* __restrict__ Wzv,
    const float* __restrict__ Wq,  const float* __restrict__ Wout,
    bf16_t* __restrict__ W, bf16_t* __restrict__ A)
{
    const int tid = threadIdx.x;
    if (blockIdx.x >= 256) {
        const int row = (blockIdx.x - 256) * 2 + (tid >> 7);
        const int c8 = (tid & 127) * 8;
        const float* src = (c8 < 512) ? (H + (size_t)row * 512 + c8)
                                      : (Z + (size_t)row * 512 + (c8 - 512));
        *reinterpret_cast<bf16x8*>(A + (size_t)row * 1024 + c8) = ld8f(src);
        return;
    }
    __shared__ bf16_t LA[64][40];
    __shared__ bf16_t LB[64][40];
    const int lane = tid & 63, wid = tid >> 6;
    const int L15 = lane & 15, qd = lane >> 4;
    const int quad = blockIdx.x & 3, tile = blockIdx.x >> 2;
    const int ti = (tile >> 3) * 64, tj = (tile & 7) * 64;
    const float RS = 0.04419417382415922f;  // 1/sqrt(512)

    const float* Lp; const float* Rp; int orow, ocol; float scale; int transL;
    switch (quad) {
        case 0:  Lp = Wq;           Rp = Whk; orow = 0;   ocol = 0;   scale = RS;  transL = 1; break;
        case 1:  Lp = Wout;         Rp = Whv; orow = 512; ocol = 0;   scale = 1.f; transL = 0; break;
        case 2:  Lp = Wq + 524288;  Rp = Wzk; orow = 0;   ocol = 512; scale = RS;  transL = 1; break;
        default: Lp = Wout + 1024;  Rp = Wzv; orow = 512; ocol = 512; scale = 1.f; transL = 0; break;
    }

    const int li  = tid & 63;
    const int lk8 = (tid >> 6) * 8;
    const int di  = tid >> 2;
    const int dk0 = (tid & 3) * 8;

    float fa[8], fb[8];
    auto loadT = [&](int kc) {
        const int k0 = kc * 32;
        if (transL) {
#pragma unroll
            for (int j = 0; j < 8; j++)
                fa[j] = Lp[(size_t)(k0 + lk8 + j) * 512 + ti + li];
        } else {
            const float* p = Lp + (size_t)(ti + di) * 2048 + k0 + dk0;
            f32x4 v0 = *reinterpret_cast<const f32x4*>(p);
            f32x4 v1 = *reinterpret_cast<const f32x4*>(p + 4);
#pragma unroll
            for (int j = 0; j < 4; j++) { fa[j] = v0[j]; fa[4 + j] = v1[j]; }
        }
#pragma unroll
        for (int j = 0; j < 8; j++)
            fb[j] = Rp[(size_t)(k0 + lk8 + j) * 512 + tj + li];
    };

    f32x4 acc[4];
#pragma unroll
    for (int t = 0; t < 4; t++) acc[t] = (f32x4){0.f, 0.f, 0.f, 0.f};

    loadT(0);
    for (int kc = 0; kc < 32; kc++) {
        __syncthreads();
        bf16x8 pa, pb;
#pragma unroll
        for (int j = 0; j < 8; j++) { pa[j] = (bf16_t)fa[j]; pb[j] = (bf16_t)fb[j]; }
        if (transL) *reinterpret_cast<bf16x8*>(&LA[li][lk8]) = pa;
        else        *reinterpret_cast<bf16x8*>(&LA[di][dk0]) = pa;
        *reinterpret_cast<bf16x8*>(&LB[li][lk8]) = pb;
        __syncthreads();
        if (kc + 1 < 32) loadT(kc + 1);
        bf16x8 afr = *reinterpret_cast<bf16x8*>(&LA[wid * 16 + L15][qd * 8]);
#pragma unroll
        for (int t = 0; t < 4; t++) {
            bf16x8 bfr = *reinterpret_cast<bf16x8*>(&LB[t * 16 + L15][qd * 8]);
            acc[t] = MFMA16(afr, bfr, acc[t]);
        }
    }
#pragma unroll
    for (int t = 0; t < 4; t++) {
        int col = ocol + tj + t * 16 + L15;
#pragma unroll
        for (int r = 0; r < 4; r++) {
            int row = orow + ti + wid * 16 + qd * 4 + r;
            W[(size_t)row * 1024 + col] = (bf16_t)(acc[t][r] * scale);
        }
    }
}

// ---------------------------------------------------------------------------
// K2 k_gemm: C[16384x1024] = A bf16 x W^T bf16.  128x128 tile, BK=64,
// lane-linear LDS layout (conflict-free for both DMA write and b128 read):
//   SA[p][g][lane]: element (p*4096 + g*512 + lane*8 + e) holds
//       A[m0 + g*16 + (lane&15)][kt*64 + p*32 + (lane>>4)*8 + e]
// Fragment (pass p, tile mt): read at p*4096 + (wy*4+mt)*512 + lane*8 -> the
// exact lane-contiguous pattern the DMA wrote.
// mb = bid&127 (same-A blocks -> same XCD L2), nb = bid>>7.
// ---------------------------------------------------------------------------
__global__ __launch_bounds__(256) void k_gemm(
    const bf16_t* __restrict__ A, const bf16_t* __restrict__ W,
    bf16_t* __restrict__ G, bf16_t* __restrict__ VT)
{
    __shared__ bf16_t SA[8192];   // 16 KB
    __shared__ bf16_t SB[8192];   // 16 KB
    const int tid = threadIdx.x, lane = tid & 63, wid = tid >> 6;
    const int L15 = lane & 15, qd = lane >> 4;
    const int mb = blockIdx.x & 127, nb = blockIdx.x >> 7;
    const int m0 = mb * 128, n0 = nb * 128;
    const int wy = wid & 1, wx = wid >> 1;
    const int rsub = lane & 15, ksub = (lane >> 4) * 8;

    f32x4 acc[4][4];
#pragma unroll
    for (int mt = 0; mt < 4; mt++)
#pragma unroll
        for (int nt = 0; nt < 4; nt++) acc[mt][nt] = (f32x4){0.f, 0.f, 0.f, 0.f};

    for (int kt = 0; kt < 16; kt++) {
        const int kc0 = kt * 64;
        __syncthreads();
#pragma unroll
        for (int j = 0; j < 2; j++) {
            const int g = wid * 2 + j;
#pragma unroll
            for (int p = 0; p < 2; p++) {
                gload_lds16(A + (size_t)(m0 + g * 16 + rsub) * 1024 + kc0 + p * 32 + ksub,
                            SA + p * 4096 + g * 512 + lane * 8);
                gload_lds16(W + (size_t)(n0 + g * 16 + rsub) * 1024 + kc0 + p * 32 + ksub,
                            SB + p * 4096 + g * 512 + lane * 8);
            }
        }
        __syncthreads();
#pragma unroll
        for (int p = 0; p < 2; p++) {
            bf16x8 af[4], bf[4];
#pragma unroll
            for (int mt = 0; mt < 4; mt++)
                af[mt] = *reinterpret_cast<bf16x8*>(&SA[p * 4096 + (wy * 4 + mt) * 512 + lane * 8]);
#pragma unroll
            for (int nt = 0; nt < 4; nt++)
                bf[nt] = *reinterpret_cast<bf16x8*>(&SB[p * 4096 + (wx * 4 + nt) * 512 + lane * 8]);
#pragma unroll
            for (int mt = 0; mt < 4; mt++)
#pragma unroll
                for (int nt = 0; nt < 4; nt++)
                    acc[mt][nt] = MFMA16(af[mt], bf[nt], acc[mt][nt]);
        }
    }

    if (nb < 4) {
#pragma unroll
        for (int mt = 0; mt < 4; mt++) {
            int mrow = m0 + wy * 64 + mt * 16 + qd * 4;
#pragma unroll
            for (int nt = 0; nt < 4; nt++) {
                int j = n0 + wx * 64 + nt * 16 + L15;
#pragma unroll
                for (int r = 0; r < 4; r++)
                    G[(size_t)(mrow + r) * 512 + j] = (bf16_t)acc[mt][nt][r];
            }
        }
    } else {
#pragma unroll
        for (int mt = 0; mt < 4; mt++) {
            int mrow = m0 + wy * 64 + mt * 16 + qd * 4;
            int n = mrow >> 6, kl = mrow & 63;
#pragma unroll
            for (int nt = 0; nt < 4; nt++) {
                int dloc = n0 - 512 + wx * 64 + nt * 16 + L15;
                bf16x4 pk;
#pragma unroll
                for (int r = 0; r < 4; r++) pk[r] = (bf16_t)acc[mt][nt][r];
                *reinterpret_cast<bf16x4*>(&VT[(size_t)n * 32768 + (size_t)dloc * 64 + kl]) = pk;
            }
        }
    }
}

// ---------------------------------------------------------------------------
// K3 k_attn: 1024 blocks x 256 thr; block = (batch n = bid&255, 16-k strip).
// Dual-accumulator logits chain (hide MFMA latency); softmax; PV; LN.
// ---------------------------------------------------------------------------
__global__ __launch_bounds__(256) void k_attn(
    const bf16_t* __restrict__ A,
    const bf16_t* __restrict__ G, const bf16_t* __restrict__ VT,
    const float* __restrict__ lng, const float* __restrict__ lnb,
    float* __restrict__ out)
{
    __shared__ float  Sl[16][68];
    __shared__ bf16_t Sp[16][72];
    __shared__ float  Rs[4][16];
    __shared__ float  Rq[4][16];
    const int n = blockIdx.x & 255, ks4 = blockIdx.x >> 8;
    const int tid = threadIdx.x, lane = tid & 63, w = tid >> 6;
    const int L15 = lane & 15, qd = lane >> 4;
    const bf16_t* Gb = G + (size_t)n * 32768 + (size_t)(ks4 * 16) * 512;
    const bf16_t* Vb = VT + (size_t)n * 32768;
    const bf16_t* Ab = A + (size_t)n * 64 * 1024;

    {   // logits[16 k-rows][q-tile w], two independent MFMA chains
        f32x4 lg0 = (f32x4){0.f, 0.f, 0.f, 0.f};
        f32x4 lg1 = (f32x4){0.f, 0.f, 0.f, 0.f};
        const bf16_t* ga = Gb + (size_t)L15 * 512 + qd * 8;
        const bf16_t* ab = Ab + (size_t)(w * 16 + L15) * 1024 + qd * 8;
#pragma unroll
        for (int ks = 0; ks < 16; ks += 2) {
            lg0 = MFMA16(ldg8(ga + ks * 32),      ldg8(ab + ks * 32),      lg0);
            lg1 = MFMA16(ldg8(ga + ks * 32 + 32), ldg8(ab + ks * 32 + 32), lg1);
        }
        f32x4 lg = lg0 + lg1;
#pragma unroll
        for (int r = 0; r < 4; r++)
            Sl[qd * 4 + r][w * 16 + L15] = lg[r];
    }
    __syncthreads();
    {   // softmax over q (64): 16 threads/row, 4 cols each
        int row = tid >> 4, c0 = (tid & 15) * 4;
        float4 v = *reinterpret_cast<float4*>(&Sl[row][c0]);
        float mx = fmaxf(fmaxf(v.x, v.y), fmaxf(v.z, v.w));
#pragma unroll
        for (int m = 1; m < 16; m <<= 1) mx = fmaxf(mx, __shfl_xor(mx, m));
        float e0 = __expf(v.x - mx), e1 = __expf(v.y - mx);
        float e2 = __expf(v.z - mx), e3 = __expf(v.w - mx);
        float s = e0 + e1 + e2 + e3;
#pragma unroll
        for (int m = 1; m < 16; m <<= 1) s += __shfl_xor(s, m);
        float inv = 1.0f / s;
        bf16x4 p;
        p[0] = (bf16_t)(e0 * inv); p[1] = (bf16_t)(e1 * inv);
        p[2] = (bf16_t)(e2 * inv); p[3] = (bf16_t)(e3 * inv);
        *reinterpret_cast<bf16x4*>(&Sp[row][c0]) = p;
    }
    __syncthreads();

    // PV: wave w -> d-chunk w*128
    f32x4 acc[8];
#pragma unroll
    for (int dt = 0; dt < 8; dt++) acc[dt] = (f32x4){0.f, 0.f, 0.f, 0.f};
#pragma unroll
    for (int kq = 0; kq < 2; kq++) {
        bf16x8 ap = *reinterpret_cast<bf16x8*>(&Sp[L15][kq * 32 + qd * 8]);
#pragma unroll
        for (int dt = 0; dt < 8; dt++) {
            bf16x8 bv = ldg8(Vb + (size_t)(w * 128 + dt * 16 + L15) * 64 + kq * 32 + qd * 8);
            acc[dt] = MFMA16(ap, bv, acc[dt]);
        }
    }
    // LayerNorm over d=512
    float s4[4] = {0.f, 0.f, 0.f, 0.f}, ss4[4] = {0.f, 0.f, 0.f, 0.f};
#pragma unroll
    for (int dt = 0; dt < 8; dt++)
#pragma unroll
        for (int r = 0; r < 4; r++) { float x = acc[dt][r]; s4[r] += x; ss4[r] += x * x; }
#pragma unroll
    for (int m = 1; m < 16; m <<= 1)
#pragma unroll
        for (int r = 0; r < 4; r++) {
            s4[r]  += __shfl_xor(s4[r], m);
            ss4[r] += __shfl_xor(ss4[r], m);
        }
    if (L15 == 0)
#pragma unroll
        for (int r = 0; r < 4; r++) {
            int row = qd * 4 + r;
            Rs[w][row] = s4[r];
            Rq[w][row] = ss4[r];
        }
    __syncthreads();
    float mean[4], rstd[4];
#pragma unroll
    for (int r = 0; r < 4; r++) {
        int row = qd * 4 + r;
        float S = Rs[0][row] + Rs[1][row] + Rs[2][row] + Rs[3][row];
        float Q = Rq[0][row] + Rq[1][row] + Rq[2][row] + Rq[3][row];
        float mu = S * (1.f / 512.f);
        float var = Q * (1.f / 512.f) - mu * mu;
        mean[r] = mu;
        rstd[r] = rsqrtf(var + 1e-5f);
    }
    float* ob = out + (size_t)n * 32768 + (size_t)(ks4 * 16) * 512;
#pragma unroll
    for (int dt = 0; dt < 8; dt++) {
        int col = w * 128 + dt * 16 + L15;
        float gg = lng[col], bb = lnb[col];
#pragma unroll
        for (int r = 0; r < 4; r++) {
            int row = qd * 4 + r;
            ob[(size_t)row * 512 + col] = (acc[dt][r] - mean[r]) * rstd[r] * gg + bb;
        }
    }
}

// ---------------------------------------------------------------------------
// Fallback fused per-batch kernel (R4-proven) — only if ws too small.
// ---------------------------------------------------------------------------
__global__ __launch_bounds__(1024) void k_batch_fb(
    const float* __restrict__ H, const float* __restrict__ Z,
    const bf16_t* __restrict__ W,
    const float* __restrict__ lng, const float* __restrict__ lnb,
    float* __restrict__ out)
{
    __shared__ __align__(16) char lds_raw[48128];
    bf16_t* lds_bf = (bf16_t*)lds_raw;
    float*  lds_f  = (float*)lds_raw;
    bf16_t* Gbuf = lds_bf;
    float*  Sl   = lds_f;
    bf16_t* VTl  = lds_bf;
    bf16_t* Sp   = lds_bf + 18432;
    float*  Rs   = lds_f + 11520;
    float*  Rq   = lds_f + 11776;

    const int n = blockIdx.x;
    const int tid = threadIdx.x, lane = tid & 63, w = tid >> 6;
    const int L15 = lane & 15, qd = lane >> 4;
    const int strip = w & 3, grp = w >> 2;
    const float* Hb = H + (size_t)n * 32768;
    const float* Zb = Z + (size_t)n * 32768;

    f32x4 a1 = (f32x4){0.f, 0.f, 0.f, 0.f};
    for (int hf = 0; hf < 2; hf++) {
        f32x4 ga[4];
#pragma unroll
        for (int mt = 0; mt < 4; mt++) ga[mt] = (f32x4){0.f, 0.f, 0.f, 0.f};
        const bf16_t* wrow = W + (size_t)(hf * 256 + w * 16 + L15) * 1024;
#pragma unroll 4
        for (int kc = 0; kc < 16; kc++) {
            const int ko = kc * 32 + qd * 8;
            bf16x8 bh = ldg8(wrow + ko);
            bf16x8 bz = ldg8(wrow + 512 + ko);
#pragma unroll
            for (int mt = 0; mt < 4; mt++) {
                bf16x8 ah = ld8f(Hb + (size_t)(mt * 16 + L15) * 512 + ko);
                bf16x8 az = ld8f(Zb + (size_t)(mt * 16 + L15) * 512 + ko);
                ga[mt] = MFMA16(ah, bh, ga[mt]);
                ga[mt] = MFMA16(az, bz, ga[mt]);
            }
        }
        __syncthreads();
#pragma unroll
        for (int mt = 0; mt < 4; mt++)
#pragma unroll
            for (int r = 0; r < 4; r++)
                Gbuf[(size_t)(mt * 16 + qd * 4 + r) * 264 + w * 16 + L15] = (bf16_t)ga[mt][r];
        __syncthreads();
#pragma unroll
        for (int kcf = 0; kcf < 8; kcf++) {
            bf16x8 af = *reinterpret_cast<bf16x8*>(
                &Gbuf[(size_t)(strip * 16 + L15) * 264 + kcf * 32 + qd * 8]);
            bf16x8 bq = ld8f(Hb + (size_t)(grp * 16 + L15) * 512 + hf * 256 + kcf * 32 + qd * 8);
            a1 = MFMA16(af, bq, a1);
        }
    }
    __syncthreads();
#pragma unroll
    for (int r = 0; r < 4; r++)
        Sl[(size_t)(strip * 16 + qd * 4 + r) * 64 + grp * 16 + L15] = a1[r];
    __syncthreads();
    {
        int row = tid >> 4, c0 = (tid & 15) * 4;
        float4 v = *reinterpret_cast<float4*>(&Sl[(size_t)row * 64 + c0]);
        float mx = fmaxf(fmaxf(v.x, v.y), fmaxf(v.z, v.w));
#pragma unroll
        for (int m = 1; m < 16; m <<= 1) mx = fmaxf(mx, __shfl_xor(mx, m));
        float e0 = __expf(v.x - mx), e1 = __expf(v.y - mx);
        float e2 = __expf(v.z - mx), e3 = __expf(v.w - mx);
        float s = e0 + e1 + e2 + e3;
#pragma unroll
        for (int m = 1; m < 16; m <<= 1) s += __shfl_xor(s, m);
        float inv = 1.0f / s;
        bf16x4 p;
        p[0] = (bf16_t)(e0 * inv); p[1] = (bf16_t)(e1 * inv);
        p[2] = (bf16_t)(e2 * inv); p[3] = (bf16_t)(e3 * inv);
        *reinterpret_cast<bf16x4*>(&Sp[(size_t)row * 72 + c0]) = p;
    }
    __syncthreads();

    f32x4 acc[8];
#pragma unroll
    for (int j = 0; j < 8; j++) acc[j] = (f32x4){0.f, 0.f, 0.f, 0.f};
    for (int hf2 = 0; hf2 < 2; hf2++) {
        f32x4 va[4];
#pragma unroll
        for (int mt = 0; mt < 4; mt++) va[mt] = (f32x4){0.f, 0.f, 0.f, 0.f};
        const bf16_t* wrow = W + (size_t)(512 + hf2 * 256 + w * 16 + L15) * 1024;
#pragma unroll 4
        for (int kc = 0; kc < 16; kc++) {
            const int ko = kc * 32 + qd * 8;
            bf16x8 bh = ldg8(wrow + ko);
            bf16x8 bz = ldg8(wrow + 512 + ko);
#pragma unroll
            for (int mt = 0; mt < 4; mt++) {
                bf16x8 ah = ld8f(Hb + (size_t)(mt * 16 + L15) * 512 + ko);
                bf16x8 az = ld8f(Zb + (size_t)(mt * 16 + L15) * 512 + ko);
                va[mt] = MFMA16(ah, bh, va[mt]);
                va[mt] = MFMA16(az, bz, va[mt]);
            }
        }
#pragma unroll
        for (int mt = 0; mt < 4; mt++) {
            bf16x4 pk;
#pragma unroll
            for (int r = 0; r < 4; r++) pk[r] = (bf16_t)va[mt][r];
            *reinterpret_cast<bf16x4*>(&VTl[(size_t)(w * 16 + L15) * 72 + mt * 16 + qd * 4]) = pk;
        }
        __syncthreads();
#pragma unroll
        for (int kcq = 0; kcq < 2; kcq++) {
            bf16x8 ap = *reinterpret_cast<bf16x8*>(
                &Sp[(size_t)(strip * 16 + L15) * 72 + kcq * 32 + qd * 8]);
#pragma unroll
            for (int dt = 0; dt < 4; dt++) {
                bf16x8 bv = *reinterpret_cast<bf16x8*>(
                    &VTl[(size_t)(grp * 64 + dt * 16 + L15) * 72 + kcq * 32 + qd * 8]);
                acc[hf2 * 4 + dt] = MFMA16(ap, bv, acc[hf2 * 4 + dt]);
            }
        }
        __syncthreads();
    }
    float s4[4] = {0.f, 0.f, 0.f, 0.f}, ss4[4] = {0.f, 0.f, 0.f, 0.f};
#pragma unroll
    for (int j = 0; j < 8; j++)
#pragma unroll
        for (int r = 0; r < 4; r++) { float x = acc[j][r]; s4[r] += x; ss4[r] += x * x; }
#pragma unroll
    for (int m = 1; m < 16; m <<= 1)
#pragma unroll
        for (int r = 0; r < 4; r++) {
            s4[r]  += __shfl_xor(s4[r], m);
            ss4[r] += __shfl_xor(ss4[r], m);
        }
    if (L15 == 0)
#pragma unroll
        for (int r = 0; r < 4; r++) {
            int row = strip * 16 + qd * 4 + r;
            Rs[grp * 64 + row] = s4[r];
            Rq[grp * 64 + row] = ss4[r];
        }
    __syncthreads();
    float mean[4], rstd[4];
#pragma unroll
    for (int r = 0; r < 4; r++) {
        int row = strip * 16 + qd * 4 + r;
        float S = Rs[row] + Rs[64 + row] + Rs[128 + row] + Rs[192 + row];
        float Q = Rq[row] + Rq[64 + row] + Rq[128 + row] + Rq[192 + row];
        float mu = S * (1.f / 512.f);
        float var = Q * (1.f / 512.f) - mu * mu;
        mean[r] = mu;
        rstd[r] = rsqrtf(var + 1e-5f);
    }
#pragma unroll
    for (int j = 0; j < 8; j++) {
        int col = (j >> 2) * 256 + grp * 64 + (j & 3) * 16 + L15;
        float gg = lng[col], bb = lnb[col];
#pragma unroll
        for (int r = 0; r < 4; r++) {
            int row = strip * 16 + qd * 4 + r;
            out[(size_t)n * 32768 + (size_t)row * 512 + col] =
                (acc[j][r] - mean[r]) * rstd[r] * gg + bb;
        }
    }
}

extern "C" void kernel_launch(void* const* d_in, const int* in_sizes, int n_in,
                              void* d_out, int out_size, void* d_ws, size_t ws_size,
                              hipStream_t stream) {
    const float* H    = (const float*)d_in[0];
    const float* Z    = (const float*)d_in[1];
    const float* Whk  = (const float*)d_in[2];
    const float* Whv  = (const float*)d_in[3];
    const float* Wzk  = (const float*)d_in[4];
    const float* Wzv  = (const float*)d_in[5];
    const float* Wq   = (const float*)d_in[6];
    const float* Wout = (const float*)d_in[7];
    const float* lng  = (const float*)d_in[8];
    const float* lnb  = (const float*)d_in[9];

    bf16_t* W  = (bf16_t*)d_ws;            // [1024][1024]    2 MiB
    bf16_t* A  = W + 1024 * 1024;          // [16384][1024]  32 MiB
    bf16_t* G  = A + (size_t)16384 * 1024; // [16384][512]   16 MiB
    bf16_t* VT = G + (size_t)16384 * 512;  // [256][512][64] 16 MiB
    const size_t need = ((size_t)1024 * 1024 + (size_t)16384 * 1024 +
                         (size_t)16384 * 512 + (size_t)256 * 512 * 64) * 2;

    if (ws_size >= need) {
        k_prep<<<8448, 256, 0, stream>>>(H, Z, Whk, Whv, Wzk, Wzv, Wq, Wout, W, A);
        k_gemm<<<1024, 256, 0, stream>>>(A, W, G, VT);
        k_attn<<<1024, 256, 0, stream>>>(A, G, VT, lng, lnb, (float*)d_out);
    } else {
        k_prep<<<256, 256, 0, stream>>>(H, Z, Whk, Whv, Wzk, Wzv, Wq, Wout, W, A);
        k_batch_fb<<<256, 1024, 0, stream>>>(H, Z, W, lng, lnb, (float*)d_out);
    }
}

// Round 8
// 226.569 us; speedup vs baseline: 1.0723x; 1.0723x over previous
//
#include <hip/hip_runtime.h>
#include <hip/hip_bf16.h>
#include <cstdint>
#include <cstddef>

typedef __bf16 bf16_t;
typedef __bf16 bf16x8 __attribute__((ext_vector_type(8)));
typedef __bf16 bf16x4 __attribute__((ext_vector_type(4)));
typedef float f32x4 __attribute__((ext_vector_type(4)));

#define MFMA16(a, b, c) __builtin_amdgcn_mfma_f32_16x16x32_bf16((a), (b), (c), 0, 0, 0)

__device__ __forceinline__ bf16x8 ld8f(const float* p) {
    f32x4 a = *reinterpret_cast<const f32x4*>(p);
    f32x4 b = *reinterpret_cast<const f32x4*>(p + 4);
    bf16x8 r;
    r[0] = (bf16_t)a[0]; r[1] = (bf16_t)a[1]; r[2] = (bf16_t)a[2]; r[3] = (bf16_t)a[3];
    r[4] = (bf16_t)b[0]; r[5] = (bf16_t)b[1]; r[6] = (bf16_t)b[2]; r[7] = (bf16_t)b[3];
    return r;
}
__device__ __forceinline__ bf16x8 ldg8(const bf16_t* p) {
    return *reinterpret_cast<const bf16x8*>(p);
}
// async global->LDS DMA, 16B/lane; lds dest = uniform base + lane*16B
__device__ __forceinline__ void gload_lds16(const bf16_t* g, bf16_t* l) {
    __builtin_amdgcn_global_load_lds((const __attribute__((address_space(1))) void*)g,
                                     (__attribute__((address_space(3))) void*)l, 16, 0, 0);
}

// ---------------------------------------------------------------------------
// K0 k_prep: blocks 0..255 = fused-weight GEMM (W bf16[1024][1024]);
//            blocks 256..8447 = pack/convert H,Z f32 -> A bf16[16384][1024].
// ---------------------------------------------------------------------------
__global__ __launch_bounds__(256) void k_prep(
    const float* __restrict__ H, const float* __restrict__ Z,
    const float* __restrict__ Whk, const float* __restrict__ Whv,
    const float* __restrict__ Wzk, const float* __restrict__ Wzv,
    const float* __restrict__ Wq,  const float* __restrict__ Wout,
    bf16_t* __restrict__ W, bf16_t* __restrict__ A)
{
    const int tid = threadIdx.x;
    if (blockIdx.x >= 256) {
        const int row = (blockIdx.x - 256) * 2 + (tid >> 7);
        const int c8 = (tid & 127) * 8;
        const float* src = (c8 < 512) ? (H + (size_t)row * 512 + c8)
                                      : (Z + (size_t)row * 512 + (c8 - 512));
        *reinterpret_cast<bf16x8*>(A + (size_t)row * 1024 + c8) = ld8f(src);
        return;
    }
    __shared__ bf16_t LA[64][40];
    __shared__ bf16_t LB[64][40];
    const int lane = tid & 63, wid = tid >> 6;
    const int L15 = lane & 15, qd = lane >> 4;
    const int quad = blockIdx.x & 3, tile = blockIdx.x >> 2;
    const int ti = (tile >> 3) * 64, tj = (tile & 7) * 64;
    const float RS = 0.04419417382415922f;  // 1/sqrt(512)

    const float* Lp; const float* Rp; int orow, ocol; float scale; int transL;
    switch (quad) {
        case 0:  Lp = Wq;           Rp = Whk; orow = 0;   ocol = 0;   scale = RS;  transL = 1; break;
        case 1:  Lp = Wout;         Rp = Whv; orow = 512; ocol = 0;   scale = 1.f; transL = 0; break;
        case 2:  Lp = Wq + 524288;  Rp = Wzk; orow = 0;   ocol = 512; scale = RS;  transL = 1; break;
        default: Lp = Wout + 1024;  Rp = Wzv; orow = 512; ocol = 512; scale = 1.f; transL = 0; break;
    }

    const int li  = tid & 63;
    const int lk8 = (tid >> 6) * 8;
    const int di  = tid >> 2;
    const int dk0 = (tid & 3) * 8;

    float fa[8], fb[8];
    auto loadT = [&](int kc) {
        const int k0 = kc * 32;
        if (transL) {
#pragma unroll
            for (int j = 0; j < 8; j++)
                fa[j] = Lp[(size_t)(k0 + lk8 + j) * 512 + ti + li];
        } else {
            const float* p = Lp + (size_t)(ti + di) * 2048 + k0 + dk0;
            f32x4 v0 = *reinterpret_cast<const f32x4*>(p);
            f32x4 v1 = *reinterpret_cast<const f32x4*>(p + 4);
#pragma unroll
            for (int j = 0; j < 4; j++) { fa[j] = v0[j]; fa[4 + j] = v1[j]; }
        }
#pragma unroll
        for (int j = 0; j < 8; j++)
            fb[j] = Rp[(size_t)(k0 + lk8 + j) * 512 + tj + li];
    };

    f32x4 acc[4];
#pragma unroll
    for (int t = 0; t < 4; t++) acc[t] = (f32x4){0.f, 0.f, 0.f, 0.f};

    loadT(0);
    for (int kc = 0; kc < 32; kc++) {
        __syncthreads();
        bf16x8 pa, pb;
#pragma unroll
        for (int j = 0; j < 8; j++) { pa[j] = (bf16_t)fa[j]; pb[j] = (bf16_t)fb[j]; }
        if (transL) *reinterpret_cast<bf16x8*>(&LA[li][lk8]) = pa;
        else        *reinterpret_cast<bf16x8*>(&LA[di][dk0]) = pa;
        *reinterpret_cast<bf16x8*>(&LB[li][lk8]) = pb;
        __syncthreads();
        if (kc + 1 < 32) loadT(kc + 1);
        bf16x8 afr = *reinterpret_cast<bf16x8*>(&LA[wid * 16 + L15][qd * 8]);
#pragma unroll
        for (int t = 0; t < 4; t++) {
            bf16x8 bfr = *reinterpret_cast<bf16x8*>(&LB[t * 16 + L15][qd * 8]);
            acc[t] = MFMA16(afr, bfr, acc[t]);
        }
    }
#pragma unroll
    for (int t = 0; t < 4; t++) {
        int col = ocol + tj + t * 16 + L15;
#pragma unroll
        for (int r = 0; r < 4; r++) {
            int row = orow + ti + wid * 16 + qd * 4 + r;
            W[(size_t)row * 1024 + col] = (bf16_t)(acc[t][r] * scale);
        }
    }
}

// ---------------------------------------------------------------------------
// K2 k_gemm: EXACT R6 structure (proven 57us): 128x128 tile, BK=32,
// global_load_lds width-16 staging, 2-barrier K-loop.
// mb = bid&127 (same-A blocks -> same XCD L2), nb = bid>>7.
// ---------------------------------------------------------------------------
__global__ __launch_bounds__(256) void k_gemm(
    const bf16_t* __restrict__ A, const bf16_t* __restrict__ W,
    bf16_t* __restrict__ G, bf16_t* __restrict__ VT)
{
    __shared__ bf16_t SA[128 * 32];
    __shared__ bf16_t SB[128 * 32];
    const int tid = threadIdx.x, lane = tid & 63, wid = tid >> 6;
    const int L15 = lane & 15, qd = lane >> 4;
    const int mb = blockIdx.x & 127, nb = blockIdx.x >> 7;
    const int m0 = mb * 128, n0 = nb * 128;
    const int wy = wid & 1, wx = wid >> 1;

    const int srow = (lane >> 2);
    const int scol = (lane & 3) * 8;

    f32x4 acc[4][4];
#pragma unroll
    for (int mt = 0; mt < 4; mt++)
#pragma unroll
        for (int nt = 0; nt < 4; nt++) acc[mt][nt] = (f32x4){0.f, 0.f, 0.f, 0.f};

    for (int kc = 0; kc < 32; kc++) {
        const int k0 = kc * 32;
        __syncthreads();
#pragma unroll
        for (int it = 0; it < 2; it++) {
            const int r = wid * 32 + it * 16 + srow;
            const int lo = (wid * 32 + it * 16) * 32 + lane * 8;
            gload_lds16(A + (size_t)(m0 + r) * 1024 + k0 + scol, SA + lo);
            gload_lds16(W + (size_t)(n0 + r) * 1024 + k0 + scol, SB + lo);
        }
        __syncthreads();
        bf16x8 af[4], bf[4];
#pragma unroll
        for (int mt = 0; mt < 4; mt++)
            af[mt] = *reinterpret_cast<bf16x8*>(&SA[(wy * 64 + mt * 16 + L15) * 32 + qd * 8]);
#pragma unroll
        for (int nt = 0; nt < 4; nt++)
            bf[nt] = *reinterpret_cast<bf16x8*>(&SB[(wx * 64 + nt * 16 + L15) * 32 + qd * 8]);
#pragma unroll
        for (int mt = 0; mt < 4; mt++)
#pragma unroll
            for (int nt = 0; nt < 4; nt++)
                acc[mt][nt] = MFMA16(af[mt], bf[nt], acc[mt][nt]);
    }

    if (nb < 4) {
#pragma unroll
        for (int mt = 0; mt < 4; mt++) {
            int mrow = m0 + wy * 64 + mt * 16 + qd * 4;
#pragma unroll
            for (int nt = 0; nt < 4; nt++) {
                int j = n0 + wx * 64 + nt * 16 + L15;
#pragma unroll
                for (int r = 0; r < 4; r++)
                    G[(size_t)(mrow + r) * 512 + j] = (bf16_t)acc[mt][nt][r];
            }
        }
    } else {
#pragma unroll
        for (int mt = 0; mt < 4; mt++) {
            int mrow = m0 + wy * 64 + mt * 16 + qd * 4;
            int n = mrow >> 6, kl = mrow & 63;
#pragma unroll
            for (int nt = 0; nt < 4; nt++) {
                int dloc = n0 - 512 + wx * 64 + nt * 16 + L15;
                bf16x4 pk;
#pragma unroll
                for (int r = 0; r < 4; r++) pk[r] = (bf16_t)acc[mt][nt][r];
                *reinterpret_cast<bf16x4*>(&VT[(size_t)n * 32768 + (size_t)dloc * 64 + kl]) = pk;
            }
        }
    }
}

// ---------------------------------------------------------------------------
// K3 k_attn: 1024 blocks x 256 thr; block = (batch n = bid&255, 16-k strip).
// NEW: VT fragments register-prefetched at entry (16 ldg8, no deps) so PV
// MFMAs fire without load stalls; logits+softmax hide the ~200cyc L2 latency.
// ---------------------------------------------------------------------------
__global__ __launch_bounds__(256) void k_attn(
    const bf16_t* __restrict__ A,
    const bf16_t* __restrict__ G, const bf16_t* __restrict__ VT,
    const float* __restrict__ lng, const float* __restrict__ lnb,
    float* __restrict__ out)
{
    __shared__ float  Sl[16][68];
    __shared__ bf16_t Sp[16][72];
    __shared__ float  Rs[4][16];
    __shared__ float  Rq[4][16];
    const int n = blockIdx.x & 255, ks4 = blockIdx.x >> 8;
    const int tid = threadIdx.x, lane = tid & 63, w = tid >> 6;
    const int L15 = lane & 15, qd = lane >> 4;
    const bf16_t* Gb = G + (size_t)n * 32768 + (size_t)(ks4 * 16) * 512;
    const bf16_t* Vb = VT + (size_t)n * 32768;
    const bf16_t* Ab = A + (size_t)n * 64 * 1024;

    // ---- prefetch all PV B-fragments (dependency-free; 64 VGPRs) ----
    bf16x8 bv[2][8];
#pragma unroll
    for (int kq = 0; kq < 2; kq++)
#pragma unroll
        for (int dt = 0; dt < 8; dt++)
            bv[kq][dt] = ldg8(Vb + (size_t)(w * 128 + dt * 16 + L15) * 64 + kq * 32 + qd * 8);

    {   // logits[16 k-rows][q-tile w], two independent MFMA chains
        f32x4 lg0 = (f32x4){0.f, 0.f, 0.f, 0.f};
        f32x4 lg1 = (f32x4){0.f, 0.f, 0.f, 0.f};
        const bf16_t* ga = Gb + (size_t)L15 * 512 + qd * 8;
        const bf16_t* ab = Ab + (size_t)(w * 16 + L15) * 1024 + qd * 8;
#pragma unroll
        for (int ks = 0; ks < 16; ks += 2) {
            lg0 = MFMA16(ldg8(ga + ks * 32),      ldg8(ab + ks * 32),      lg0);
            lg1 = MFMA16(ldg8(ga + ks * 32 + 32), ldg8(ab + ks * 32 + 32), lg1);
        }
        f32x4 lg = lg0 + lg1;
#pragma unroll
        for (int r = 0; r < 4; r++)
            Sl[qd * 4 + r][w * 16 + L15] = lg[r];
    }
    __syncthreads();
    {   // softmax over q (64): 16 threads/row, 4 cols each
        int row = tid >> 4, c0 = (tid & 15) * 4;
        float4 v = *reinterpret_cast<float4*>(&Sl[row][c0]);
        float mx = fmaxf(fmaxf(v.x, v.y), fmaxf(v.z, v.w));
#pragma unroll
        for (int m = 1; m < 16; m <<= 1) mx = fmaxf(mx, __shfl_xor(mx, m));
        float e0 = __expf(v.x - mx), e1 = __expf(v.y - mx);
        float e2 = __expf(v.z - mx), e3 = __expf(v.w - mx);
        float s = e0 + e1 + e2 + e3;
#pragma unroll
        for (int m = 1; m < 16; m <<= 1) s += __shfl_xor(s, m);
        float inv = 1.0f / s;
        bf16x4 p;
        p[0] = (bf16_t)(e0 * inv); p[1] = (bf16_t)(e1 * inv);
        p[2] = (bf16_t)(e2 * inv); p[3] = (bf16_t)(e3 * inv);
        *reinterpret_cast<bf16x4*>(&Sp[row][c0]) = p;
    }
    __syncthreads();

    // PV from prefetched registers: wave w -> d-chunk w*128
    f32x4 acc[8];
#pragma unroll
    for (int dt = 0; dt < 8; dt++) acc[dt] = (f32x4){0.f, 0.f, 0.f, 0.f};
#pragma unroll
    for (int kq = 0; kq < 2; kq++) {
        bf16x8 ap = *reinterpret_cast<bf16x8*>(&Sp[L15][kq * 32 + qd * 8]);
#pragma unroll
        for (int dt = 0; dt < 8; dt++)
            acc[dt] = MFMA16(ap, bv[kq][dt], acc[dt]);
    }
    // LayerNorm over d=512
    float s4[4] = {0.f, 0.f, 0.f, 0.f}, ss4[4] = {0.f, 0.f, 0.f, 0.f};
#pragma unroll
    for (int dt = 0; dt < 8; dt++)
#pragma unroll
        for (int r = 0; r < 4; r++) { float x = acc[dt][r]; s4[r] += x; ss4[r] += x * x; }
#pragma unroll
    for (int m = 1; m < 16; m <<= 1)
#pragma unroll
        for (int r = 0; r < 4; r++) {
            s4[r]  += __shfl_xor(s4[r], m);
            ss4[r] += __shfl_xor(ss4[r], m);
        }
    if (L15 == 0)
#pragma unroll
        for (int r = 0; r < 4; r++) {
            int row = qd * 4 + r;
            Rs[w][row] = s4[r];
            Rq[w][row] = ss4[r];
        }
    __syncthreads();
    float mean[4], rstd[4];
#pragma unroll
    for (int r = 0; r < 4; r++) {
        int row = qd * 4 + r;
        float S = Rs[0][row] + Rs[1][row] + Rs[2][row] + Rs[3][row];
        float Q = Rq[0][row] + Rq[1][row] + Rq[2][row] + Rq[3][row];
        float mu = S * (1.f / 512.f);
        float var = Q * (1.f / 512.f) - mu * mu;
        mean[r] = mu;
        rstd[r] = rsqrtf(var + 1e-5f);
    }
    float* ob = out + (size_t)n * 32768 + (size_t)(ks4 * 16) * 512;
#pragma unroll
    for (int dt = 0; dt < 8; dt++) {
        int col = w * 128 + dt * 16 + L15;
        float gg = lng[col], bb = lnb[col];
#pragma unroll
        for (int r = 0; r < 4; r++) {
            int row = qd * 4 + r;
            ob[(size_t)row * 512 + col] = (acc[dt][r] - mean[r]) * rstd[r] * gg + bb;
        }
    }
}

// ---------------------------------------------------------------------------
// Fallback fused per-batch kernel (R4-proven) — only if ws too small.
// ---------------------------------------------------------------------------
__global__ __launch_bounds__(1024) void k_batch_fb(
    const float* __restrict__ H, const float* __restrict__ Z,
    const bf16_t* __restrict__ W,
    const float* __restrict__ lng, const float* __restrict__ lnb,
    float* __restrict__ out)
{
    __shared__ __align__(16) char lds_raw[48128];
    bf16_t* lds_bf = (bf16_t*)lds_raw;
    float*  lds_f  = (float*)lds_raw;
    bf16_t* Gbuf = lds_bf;
    float*  Sl   = lds_f;
    bf16_t* VTl  = lds_bf;
    bf16_t* Sp   = lds_bf + 18432;
    float*  Rs   = lds_f + 11520;
    float*  Rq   = lds_f + 11776;

    const int n = blockIdx.x;
    const int tid = threadIdx.x, lane = tid & 63, w = tid >> 6;
    const int L15 = lane & 15, qd = lane >> 4;
    const int strip = w & 3, grp = w >> 2;
    const float* Hb = H + (size_t)n * 32768;
    const float* Zb = Z + (size_t)n * 32768;

    f32x4 a1 = (f32x4){0.f, 0.f, 0.f, 0.f};
    for (int hf = 0; hf < 2; hf++) {
        f32x4 ga[4];
#pragma unroll
        for (int mt = 0; mt < 4; mt++) ga[mt] = (f32x4){0.f, 0.f, 0.f, 0.f};
        const bf16_t* wrow = W + (size_t)(hf * 256 + w * 16 + L15) * 1024;
#pragma unroll 4
        for (int kc = 0; kc < 16; kc++) {
            const int ko = kc * 32 + qd * 8;
            bf16x8 bh = ldg8(wrow + ko);
            bf16x8 bz = ldg8(wrow + 512 + ko);
#pragma unroll
            for (int mt = 0; mt < 4; mt++) {
                bf16x8 ah = ld8f(Hb + (size_t)(mt * 16 + L15) * 512 + ko);
                bf16x8 az = ld8f(Zb + (size_t)(mt * 16 + L15) * 512 + ko);
                ga[mt] = MFMA16(ah, bh, ga[mt]);
                ga[mt] = MFMA16(az, bz, ga[mt]);
            }
        }
        __syncthreads();
#pragma unroll
        for (int mt = 0; mt < 4; mt++)
#pragma unroll
            for (int r = 0; r < 4; r++)
                Gbuf[(size_t)(mt * 16 + qd * 4 + r) * 264 + w * 16 + L15] = (bf16_t)ga[mt][r];
        __syncthreads();
#pragma unroll
        for (int kcf = 0; kcf < 8; kcf++) {
            bf16x8 af = *reinterpret_cast<bf16x8*>(
                &Gbuf[(size_t)(strip * 16 + L15) * 264 + kcf * 32 + qd * 8]);
            bf16x8 bq = ld8f(Hb + (size_t)(grp * 16 + L15) * 512 + hf * 256 + kcf * 32 + qd * 8);
            a1 = MFMA16(af, bq, a1);
        }
    }
    __syncthreads();
#pragma unroll
    for (int r = 0; r < 4; r++)
        Sl[(size_t)(strip * 16 + qd * 4 + r) * 64 + grp * 16 + L15] = a1[r];
    __syncthreads();
    {
        int row = tid >> 4, c0 = (tid & 15) * 4;
        float4 v = *reinterpret_cast<float4*>(&Sl[(size_t)row * 64 + c0]);
        float mx = fmaxf(fmaxf(v.x, v.y), fmaxf(v.z, v.w));
#pragma unroll
        for (int m = 1; m < 16; m <<= 1) mx = fmaxf(mx, __shfl_xor(mx, m));
        float e0 = __expf(v.x - mx), e1 = __expf(v.y - mx);
        float e2 = __expf(v.z - mx), e3 = __expf(v.w - mx);
        float s = e0 + e1 + e2 + e3;
#pragma unroll
        for (int m = 1; m < 16; m <<= 1) s += __shfl_xor(s, m);
        float inv = 1.0f / s;
        bf16x4 p;
        p[0] = (bf16_t)(e0 * inv); p[1] = (bf16_t)(e1 * inv);
        p[2] = (bf16_t)(e2 * inv); p[3] = (bf16_t)(e3 * inv);
        *reinterpret_cast<bf16x4*>(&Sp[(size_t)row * 72 + c0]) = p;
    }
    __syncthreads();

    f32x4 acc[8];
#pragma unroll
    for (int j = 0; j < 8; j++) acc[j] = (f32x4){0.f, 0.f, 0.f, 0.f};
    for (int hf2 = 0; hf2 < 2; hf2++) {
        f32x4 va[4];
#pragma unroll
        for (int mt = 0; mt < 4; mt++) va[mt] = (f32x4){0.f, 0.f, 0.f, 0.f};
        const bf16_t* wrow = W + (size_t)(512 + hf2 * 256 + w * 16 + L15) * 1024;
#pragma unroll 4
        for (int kc = 0; kc < 16; kc++) {
            const int ko = kc * 32 + qd * 8;
            bf16x8 bh = ldg8(wrow + ko);
            bf16x8 bz = ldg8(wrow + 512 + ko);
#pragma unroll
            for (int mt = 0; mt < 4; mt++) {
                bf16x8 ah = ld8f(Hb + (size_t)(mt * 16 + L15) * 512 + ko);
                bf16x8 az = ld8f(Zb + (size_t)(mt * 16 + L15) * 512 + ko);
                va[mt] = MFMA16(ah, bh, va[mt]);
                va[mt] = MFMA16(az, bz, va[mt]);
            }
        }
#pragma unroll
        for (int mt = 0; mt < 4; mt++) {
            bf16x4 pk;
#pragma unroll
            for (int r = 0; r < 4; r++) pk[r] = (bf16_t)va[mt][r];
            *reinterpret_cast<bf16x4*>(&VTl[(size_t)(w * 16 + L15) * 72 + mt * 16 + qd * 4]) = pk;
        }
        __syncthreads();
#pragma unroll
        for (int kcq = 0; kcq < 2; kcq++) {
            bf16x8 ap = *reinterpret_cast<bf16x8*>(
                &Sp[(size_t)(strip * 16 + L15) * 72 + kcq * 32 + qd * 8]);
#pragma unroll
            for (int dt = 0; dt < 4; dt++) {
                bf16x8 bvl = *reinterpret_cast<bf16x8*>(
                    &VTl[(size_t)(grp * 64 + dt * 16 + L15) * 72 + kcq * 32 + qd * 8]);
                acc[hf2 * 4 + dt] = MFMA16(ap, bvl, acc[hf2 * 4 + dt]);
            }
        }
        __syncthreads();
    }
    float s4[4] = {0.f, 0.f, 0.f, 0.f}, ss4[4] = {0.f, 0.f, 0.f, 0.f};
#pragma unroll
    for (int j = 0; j < 8; j++)
#pragma unroll
        for (int r = 0; r < 4; r++) { float x = acc[j][r]; s4[r] += x; ss4[r] += x * x; }
#pragma unroll
    for (int m = 1; m < 16; m <<= 1)
#pragma unroll
        for (int r = 0; r < 4; r++) {
            s4[r]  += __shfl_xor(s4[r], m);
            ss4[r] += __shfl_xor(ss4[r], m);
        }
    if (L15 == 0)
#pragma unroll
        for (int r = 0; r < 4; r++) {
            int row = strip * 16 + qd * 4 + r;
            Rs[grp * 64 + row] = s4[r];
            Rq[grp * 64 + row] = ss4[r];
        }
    __syncthreads();
    float mean[4], rstd[4];
#pragma unroll
    for (int r = 0; r < 4; r++) {
        int row = strip * 16 + qd * 4 + r;
        float S = Rs[row] + Rs[64 + row] + Rs[128 + row] + Rs[192 + row];
        float Q = Rq[row] + Rq[64 + row] + Rq[128 + row] + Rq[192 + row];
        float mu = S * (1.f / 512.f);
        float var = Q * (1.f / 512.f) - mu * mu;
        mean[r] = mu;
        rstd[r] = rsqrtf(var + 1e-5f);
    }
#pragma unroll
    for (int j = 0; j < 8; j++) {
        int col = (j >> 2) * 256 + grp * 64 + (j & 3) * 16 + L15;
        float gg = lng[col], bb = lnb[col];
#pragma unroll
        for (int r = 0; r < 4; r++) {
            int row = strip * 16 + qd * 4 + r;
            out[(size_t)n * 32768 + (size_t)row * 512 + col] =
                (acc[j][r] - mean[r]) * rstd[r] * gg + bb;
        }
    }
}

extern "C" void kernel_launch(void* const* d_in, const int* in_sizes, int n_in,
                              void* d_out, int out_size, void* d_ws, size_t ws_size,
                              hipStream_t stream) {
    const float* H    = (const float*)d_in[0];
    const float* Z    = (const float*)d_in[1];
    const float* Whk  = (const float*)d_in[2];
    const float* Whv  = (const float*)d_in[3];
    const float* Wzk  = (const float*)d_in[4];
    const float* Wzv  = (const float*)d_in[5];
    const float* Wq   = (const float*)d_in[6];
    const float* Wout = (const float*)d_in[7];
    const float* lng  = (const float*)d_in[8];
    const float* lnb  = (const float*)d_in[9];

    bf16_t* W  = (bf16_t*)d_ws;            // [1024][1024]    2 MiB
    bf16_t* A  = W + 1024 * 1024;          // [16384][1024]  32 MiB
    bf16_t* G  = A + (size_t)16384 * 1024; // [16384][512]   16 MiB
    bf16_t* VT = G + (size_t)16384 * 512;  // [256][512][64] 16 MiB
    const size_t need = ((size_t)1024 * 1024 + (size_t)16384 * 1024 +
                         (size_t)16384 * 512 + (size_t)256 * 512 * 64) * 2;

    if (ws_size >= need) {
        k_prep<<<8448, 256, 0, stream>>>(H, Z, Whk, Whv, Wzk, Wzv, Wq, Wout, W, A);
        k_gemm<<<1024, 256, 0, stream>>>(A, W, G, VT);
        k_attn<<<1024, 256, 0, stream>>>(A, G, VT, lng, lnb, (float*)d_out);
    } else {
        k_prep<<<256, 256, 0, stream>>>(H, Z, Whk, Whv, Wzk, Wzv, Wq, Wout, W, A);
        k_batch_fb<<<256, 1024, 0, stream>>>(H, Z, W, lng, lnb, (float*)d_out);
    }
}